// Round 2
// baseline (214.826 us; speedup 1.0000x reference)
//
#include <hip/hip_runtime.h>
#include <hip/hip_bf16.h>
#include <stdint.h>

// MMD loss: L=8192 total rows, D=1024, n=4096 per half.
// result = (Sum_ss + Sum_tt - Sum_cross) / (5 n^2), bandwidth closed-form:
//   sum(d2) = 2L*sum(sq) - 2*||colsum||^2   (diagonal contributes exactly 0)

#define L_TOTAL 8192
#define D_FEAT  1024
#define N_HALF  4096
#define TILE    128
#define TTILES  64                      // L/TILE
#define NBLK    (TTILES*(TTILES+1)/2)   // 2080 lower-triangle tiles (2080%8==0)
#define BK      64                      // K-step: 128B rows -> full 8-slot swizzle

typedef __bf16 bf16_t;
typedef __bf16 bf16x8_t __attribute__((ext_vector_type(8)));
typedef float  f32x4_t  __attribute__((ext_vector_type(4)));

// workspace layout (bytes)
#define XB_OFF   0                              // bf16 X [8192][1024] = 16 MB
#define SQ_OFF   (L_TOTAL * D_FEAT * 2)         // f32 sq[8192]
#define COL_OFF  (SQ_OFF + L_TOTAL * 4)         // f32 colsum[1024]
#define SACC_OFF (COL_OFF + D_FEAT * 4)         // double S_acc
#define C0_OFF   (SACC_OFF + 8)                 // float c0 = log2e/bandwidth

__device__ __forceinline__ void async_ld16(void* lds, const void* g) {
  auto ldsp = (__attribute__((address_space(3))) void*)(uintptr_t)lds;
  auto gp   = (const __attribute__((address_space(1))) void*)(uintptr_t)g;
  __builtin_amdgcn_global_load_lds(gp, ldsp, 16, 0, 0);  // lane i -> base + i*16
}

// --- kernel 0: zero the atomic targets (ws is re-poisoned 0xAA every launch)
extern "C" __global__ __launch_bounds__(256) void k_zero(
    float* __restrict__ colsum, double* __restrict__ S_acc)
{
  const int tid = threadIdx.x;
  for (int c = tid; c < D_FEAT; c += 256) colsum[c] = 0.f;
  if (tid == 0) *S_acc = 0.0;
}

// --- kernel 1 (fused): cast rows to bf16 + per-row sum-of-squares (of the
//     bf16-rounded values, matching the Gram matrix) + fp32 column sums.
//     One pass over the 33.5 MB input. 128 blocks x 256 threads; each wave
//     owns 16 consecutive rows; lane owns 16 consecutive columns.
extern "C" __global__ __launch_bounds__(256) void k_prep(
    const float* __restrict__ src, const float* __restrict__ tgt,
    bf16_t* __restrict__ Xb, float* __restrict__ sq, float* __restrict__ colsum)
{
  __shared__ float cs[4][D_FEAT];               // per-wave colsum partials, 16KB
  const int tid  = threadIdx.x;
  const int lane = tid & 63;
  const int w    = tid >> 6;
  const int rbase = blockIdx.x * 64 + w * 16;

  float csp[16];
  #pragma unroll
  for (int j = 0; j < 16; ++j) csp[j] = 0.f;

  for (int i = 0; i < 16; ++i) {
    const int row = rbase + i;
    const float* xr = (row < N_HALF) ? (src + (size_t)row * D_FEAT)
                                     : (tgt + (size_t)(row - N_HALF) * D_FEAT);
    const float4* xv = (const float4*)(xr + lane * 16);
    float4 v[4];
    #pragma unroll
    for (int q = 0; q < 4; ++q) v[q] = xv[q];

    bf16x8_t b0, b1;
    float s = 0.f;
    #pragma unroll
    for (int q = 0; q < 4; ++q) {
      const float f0 = v[q].x, f1 = v[q].y, f2 = v[q].z, f3 = v[q].w;
      bf16_t c0 = (bf16_t)f0, c1 = (bf16_t)f1, c2 = (bf16_t)f2, c3 = (bf16_t)f3;
      if (q < 2) { b0[q*4+0]=c0; b0[q*4+1]=c1; b0[q*4+2]=c2; b0[q*4+3]=c3; }
      else       { b1[(q-2)*4+0]=c0; b1[(q-2)*4+1]=c1; b1[(q-2)*4+2]=c2; b1[(q-2)*4+3]=c3; }
      float g0=(float)c0, g1=(float)c1, g2=(float)c2, g3=(float)c3;
      s += g0*g0 + g1*g1 + g2*g2 + g3*g3;
      csp[q*4+0] += f0; csp[q*4+1] += f1; csp[q*4+2] += f2; csp[q*4+3] += f3;
    }
    bf16_t* xb = Xb + (size_t)row * D_FEAT + lane * 16;
    *(bf16x8_t*)xb = b0;
    *(bf16x8_t*)(xb + 8) = b1;

    #pragma unroll
    for (int off = 32; off > 0; off >>= 1) s += __shfl_down(s, off);
    if (lane == 0) sq[row] = s;
  }

  #pragma unroll
  for (int j = 0; j < 16; ++j) cs[w][lane * 16 + j] = csp[j];
  __syncthreads();
  #pragma unroll
  for (int k = 0; k < 4; ++k) {
    const int c = tid * 4 + k;
    atomicAdd(&colsum[c], cs[0][c] + cs[1][c] + cs[2][c] + cs[3][c]);
  }
}

// --- kernel 2: bandwidth = (2L*sum(sq) - 2*||colsum||^2)/(L^2-L)/4
extern "C" __global__ __launch_bounds__(1024) void k_bw(
    const float* __restrict__ sq, const float* __restrict__ colsum,
    float* __restrict__ c0out)
{
  const int tid = threadIdx.x;
  double t = 0.0;
  for (int i = tid; i < L_TOTAL; i += 1024) t += (double)sq[i];
  t *= 2.0 * (double)L_TOTAL;
  if (tid < D_FEAT) { double v = colsum[tid]; t -= 2.0 * v * v; }
  __shared__ double red[1024];
  red[tid] = t;
  __syncthreads();
  for (int off = 512; off > 0; off >>= 1) {
    if (tid < off) red[tid] += red[tid + off];
    __syncthreads();
  }
  if (tid == 0) {
    double bw = red[0] / ((double)L_TOTAL * (double)L_TOTAL - (double)L_TOTAL);
    bw = bw / 4.0;                               // KERNEL_MUL ** (KERNEL_NUM//2)
    *c0out = (float)(1.4426950408889634 / bw);   // log2(e)/bandwidth
  }
}

// --- kernel 3: fused Gram-MFMA + RBF + signed reduction, lower-triangle tiles.
//     BK=64, XOR-swizzled LDS (slot ^= row&7) via pre-swizzled global source
//     (global_load_lds writes linearly: rule "both-sides-or-neither").
extern "C" __global__ __launch_bounds__(256) void k_mmd(
    const bf16_t* __restrict__ Xb, const float* __restrict__ sq,
    const float* __restrict__ c0ptr, double* __restrict__ S_acc)
{
  __shared__ bf16_t As[TILE * BK];   // [128 rows][64 elem] = 16KB
  __shared__ bf16_t Bs[TILE * BK];
  __shared__ float  red[256];

  // XCD-aware bijective swizzle (NBLK % 8 == 0): consecutive tiles share a panel
  const int b = (blockIdx.x & 7) * (NBLK / 8) + (blockIdx.x >> 3);
  int ti = (int)((sqrtf(8.f * (float)b + 1.f) - 1.f) * 0.5f);
  while ((ti + 1) * (ti + 2) / 2 <= b) ++ti;
  while (ti * (ti + 1) / 2 > b) --ti;
  const int tj = b - ti * (ti + 1) / 2;          // tj <= ti
  const int row0 = ti * TILE, col0 = tj * TILE;

  const int tid  = threadIdx.x;
  const int lane = tid & 63;
  const int w    = tid >> 6;         // 4 waves, 2x2 over the 128x128 tile
  const int wr   = w >> 1, wc = w & 1;

  f32x4_t acc[4][4] = {};            // wave computes 64x64 = 4x4 frags of 16x16

  // staging: chunk ch = 8 rows x 128B; lane -> (srow, phys slot lane&7).
  // phys slot (lane&7) must hold global slot (lane&7)^srow  (involution).
  const int srow = lane >> 3;                    // 0..7
  const int scol = ((lane & 7) ^ srow) * 8;      // pre-swizzled source column

  for (int k0 = 0; k0 < D_FEAT; k0 += BK) {
    #pragma unroll
    for (int q = 0; q < 4; ++q) {
      const int ch = w * 4 + q;                  // 16 chunks per matrix
      const bf16_t* gA = Xb + (size_t)(row0 + ch * 8 + srow) * D_FEAT + k0 + scol;
      const bf16_t* gB = Xb + (size_t)(col0 + ch * 8 + srow) * D_FEAT + k0 + scol;
      async_ld16(&As[ch * 512], gA);             // wave-uniform LDS base
      async_ld16(&Bs[ch * 512], gB);
    }
    __syncthreads();                 // drains vmcnt -> tiles visible

    // swizzled reads: global slot s of row r lives at phys slot s^(r&7).
    // 16 lanes/frag-read cover 8 distinct 16B slots -> 2-way (free).
    bf16x8_t af[2][4], bfr[2][4];
    #pragma unroll
    for (int kk = 0; kk < 2; ++kk) {
      const int slot = kk * 4 + (lane >> 4);     // nominal 16B slot 0..7
      #pragma unroll
      for (int m = 0; m < 4; ++m) {
        const int r = wr * 64 + m * 16 + (lane & 15);
        af[kk][m] = *(const bf16x8_t*)&As[r * BK + (slot ^ (r & 7)) * 8];
      }
      #pragma unroll
      for (int n = 0; n < 4; ++n) {
        const int r = wc * 64 + n * 16 + (lane & 15);
        bfr[kk][n] = *(const bf16x8_t*)&Bs[r * BK + (slot ^ (r & 7)) * 8];
      }
    }
    #pragma unroll
    for (int kk = 0; kk < 2; ++kk)
      #pragma unroll
      for (int m = 0; m < 4; ++m)
        #pragma unroll
        for (int n = 0; n < 4; ++n)
          acc[m][n] = __builtin_amdgcn_mfma_f32_16x16x32_bf16(af[kk][m], bfr[kk][n], acc[m][n], 0, 0, 0);
    __syncthreads();
  }

  // epilogue: d2 -> 5-scale RBF via 1 exp2 + 4 squarings; signed partial sum
  const float c0   = *c0ptr;
  const float sgn  = ((ti < TTILES / 2) == (tj < TTILES / 2)) ? 1.f : -1.f;
  const float wgt  = (ti == tj ? 1.f : 2.f) * sgn;
  float part = 0.f;
  const int colb = col0 + wc * 64 + (lane & 15);
  const int rowb = row0 + wr * 64 + (lane >> 4) * 4;   // C/D map: col=lane&15, row=(lane>>4)*4+reg
  #pragma unroll
  for (int m = 0; m < 4; ++m) {
    #pragma unroll
    for (int n = 0; n < 4; ++n) {
      const float sqj = sq[colb + n * 16];
      #pragma unroll
      for (int r = 0; r < 4; ++r) {
        const float sqi = sq[rowb + m * 16 + r];
        float d2 = sqi + sqj - 2.f * acc[m][n][r];
        d2 = fmaxf(d2, 0.f);
        const float t  = d2 * c0;
        const float e  = __builtin_amdgcn_exp2f(-0.0625f * t); // exp(-d2/(bw*16))
        const float e2 = e * e, e4 = e2 * e2, e8 = e4 * e4, e16 = e8 * e8;
        part += e + e2 + e4 + e8 + e16;
      }
    }
  }
  part *= wgt;

  red[tid] = part;
  __syncthreads();
  for (int off = 128; off > 0; off >>= 1) {
    if (tid < off) red[tid] += red[tid + off];
    __syncthreads();
  }
  if (tid == 0) atomicAdd(S_acc, (double)red[0]);   // double: keeps S error << budget
}

// --- kernel 4: finalize
extern "C" __global__ void k_fin(const double* __restrict__ S_acc, float* __restrict__ out)
{
  out[0] = (float)(*S_acc / (5.0 * (double)N_HALF * (double)N_HALF));
}

extern "C" void kernel_launch(void* const* d_in, const int* in_sizes, int n_in,
                              void* d_out, int out_size, void* d_ws, size_t ws_size,
                              hipStream_t stream) {
  const float* src = (const float*)d_in[0];
  const float* tgt = (const float*)d_in[1];
  float* out = (float*)d_out;
  char* ws = (char*)d_ws;
  bf16_t* Xb     = (bf16_t*)(ws + XB_OFF);
  float*  sq     = (float*)(ws + SQ_OFF);
  float*  colsum = (float*)(ws + COL_OFF);
  double* S_acc  = (double*)(ws + SACC_OFF);
  float*  c0     = (float*)(ws + C0_OFF);

  k_zero<<<1, 256, 0, stream>>>(colsum, S_acc);
  k_prep<<<128, 256, 0, stream>>>(src, tgt, Xb, sq, colsum);
  k_bw  <<<1, 1024, 0, stream>>>(sq, colsum, c0);
  k_mmd <<<NBLK, 256, 0, stream>>>(Xb, sq, c0, S_acc);
  k_fin <<<1, 1, 0, stream>>>(S_acc, out);
}